// Round 17
// baseline (292.045 us; speedup 1.0000x reference)
//
#include <hip/hip_runtime.h>

// MipMap: out = relu(interp(G)+b1)@W2 + b2, G = sum_l b_l * blur_l(base@W1).
// Blur acts on spatial axes, W1 on the feature axis -> commute; interp linear.
// Ledger: R30 PASSED 287.9 = best (kblur frozen R16 body 141us/FETCH 134/
// WRITE 365 -- 5x reproduced; kgather scalar-4pt; kgemm cvt_pk A-convert:
// NEUTRAL -0.8us -> kgemm is NOT VALU-bound; its ~55us at 1.2 TB/s logical
// = latency-bound at 16 waves/CU (1024 blk x 4 waves, 50% occupancy).
// R31 = R30 + one delta: kgemm 512 threads (8 waves), wave = 16 rows x 64
// cols (4 accs, 4 B-loads, 4 MFMA/kc -- half the dependent chain, 2x the
// resident waves = 32/CU). Same tile, same LDS, same epilogue shape (stride
// 512). A-rows read by 2 waves -> L1/L2 hit within block. kblur/kgather/
// ktrans/kconvW bit-identical to R30.
// Failure: total >= 287.9 -> revert to R30 and declare plateau.
// Style: no cstdint, no unions, no templates (R9's build-fix delta).

typedef short short8 __attribute__((ext_vector_type(8)));
typedef float f32x4 __attribute__((ext_vector_type(4)));
typedef unsigned int u32x4 __attribute__((ext_vector_type(4)));

__device__ __forceinline__ unsigned short f2bfbits(float f) {
    unsigned int x = __float_as_uint(f);
    x += 0x7fffu + ((x >> 16) & 1u);   // round-to-nearest-even
    return (unsigned short)(x >> 16);
}

__device__ __forceinline__ unsigned int cvtpk_bf16(float lo, float hi) {
    unsigned int r;
    asm("v_cvt_pk_bf16_f32 %0, %1, %2" : "=v"(r) : "v"(lo), "v"(hi));
    return r;
}

__device__ __forceinline__ float bflo(unsigned int u) {
    return __uint_as_float(u << 16);
}

__device__ __forceinline__ float bfhi(unsigned int u) {
    return __uint_as_float(u & 0xffff0000u);
}

// W1 (k,n) f32 -> W1T (n,k) bf16; thread (0,0) additionally builds the coef
// table (independent output, no sync needed): coef[0..63] horiz taps,
// coef[64..127] vert taps * b_level, coef[128] b0.
__global__ void kconvW(const float* W1, unsigned short* W1T,
                       const float* blev, float* coef) {
    int i = blockIdx.x * 256 + threadIdx.x;   // 16384
    int k = i >> 7;
    int n = i & 127;
    W1T[n * 128 + k] = f2bfbits(W1[i]);
    if (blockIdx.x == 0 && threadIdx.x == 0) {
        int offs[6];
        offs[0] = 0; offs[1] = 0; offs[2] = 2; offs[3] = 6; offs[4] = 14; offs[5] = 30;
        for (int l = 1; l <= 5; l++) {
            int s = 1 << l;
            int off = offs[l];
            float sum = 0.0f;
            for (int m = 0; m < s; m++) {
                float x = ((float)m - (float)(s - 1) * 0.5f) / ((float)s * 0.5f);
                float w = expf(-0.5f * x * x);
                coef[off + m] = w;
                sum += w;
            }
            float bl = blev[l];
            for (int m = 0; m < s; m++) {
                float w = coef[off + m] / sum;
                coef[off + m] = w;
                coef[64 + off + m] = w * bl;
            }
        }
        coef[128] = blev[0];
    }
}

// MFMA GEMM: G0p(64 planes of 65536 x 2 f32) = base @ W1, plane layout.
// 512 threads = 8 waves; wave (rowg=wv&3, colg=wv>>2) computes 16 rows x
// 64 cols: 4 accs, 4 B-loads, 4 MFMA per kc (half the per-wave dependent
// chain of R30; 32 waves/CU). A-frag via v_cvt_pk_bf16_f32. D layout:
// m_off=quad*4+r, n=colg*64+c*16+(lane&15) (guide-verified m89/m91).
// Epilogue stages 64x128 tile in LDS (stride 132), writes f32 pair-planes.
__global__ void kgemm(const float* base, const unsigned short* W1T,
                      float* G0p) {
    __shared__ float stg[64 * 132];
    int tid = threadIdx.x;
    int wv = tid >> 6;                // 0..7
    int lane = tid & 63;
    int colI = lane & 15;
    int quad = lane >> 4;
    int rowg = wv & 3;                // 16-row group
    int colg = wv >> 2;               // 64-col group
    int m0 = blockIdx.x * 64 + rowg * 16;
    f32x4 zero = {0.0f, 0.0f, 0.0f, 0.0f};
    f32x4 acc0 = zero; f32x4 acc1 = zero; f32x4 acc2 = zero; f32x4 acc3 = zero;
    for (int kc = 0; kc < 4; kc++) {
        int k0 = kc * 32 + quad * 8;
        const float* ap = base + (size_t)(m0 + colI) * 128 + k0;
        f32x4 af0 = *(const f32x4*)(ap);
        f32x4 af1 = *(const f32x4*)(ap + 4);
        u32x4 au;
        au[0] = cvtpk_bf16(af0[0], af0[1]);
        au[1] = cvtpk_bf16(af0[2], af0[3]);
        au[2] = cvtpk_bf16(af1[0], af1[1]);
        au[3] = cvtpk_bf16(af1[2], af1[3]);
        short8 a = *(short8*)&au;
        const unsigned short* wb = W1T + (size_t)(colg * 64 + colI) * 128 + k0;
        short8 b0 = *(const short8*)(wb + 0 * 16 * 128);
        short8 b1 = *(const short8*)(wb + 1 * 16 * 128);
        short8 b2 = *(const short8*)(wb + 2 * 16 * 128);
        short8 b3 = *(const short8*)(wb + 3 * 16 * 128);
        acc0 = __builtin_amdgcn_mfma_f32_16x16x32_bf16(a, b0, acc0, 0, 0, 0);
        acc1 = __builtin_amdgcn_mfma_f32_16x16x32_bf16(a, b1, acc1, 0, 0, 0);
        acc2 = __builtin_amdgcn_mfma_f32_16x16x32_bf16(a, b2, acc2, 0, 0, 0);
        acc3 = __builtin_amdgcn_mfma_f32_16x16x32_bf16(a, b3, acc3, 0, 0, 0);
    }
    // stage to LDS: stg[(n>>1)*132 + m_local*2 + (n&1)], m_local in [0,64)
    int mlb = (rowg * 16 + quad * 4) * 2;
#define STG(c, A) { int n = colg * 64 + c * 16 + colI; \
    float* p = stg + (n >> 1) * 132 + mlb + (n & 1); \
    p[0] = A[0]; p[2] = A[1]; p[4] = A[2]; p[6] = A[3]; }
    STG(0, acc0) STG(1, acc1) STG(2, acc2) STG(3, acc3)
#undef STG
    __syncthreads();
    size_t m0b2 = (size_t)blockIdx.x * 128;   // m0_block * 2
    for (int j = tid; j < 2048; j += 512) {
        int fp = j >> 5;
        int q = (j & 31) * 4;
        f32x4 v = *(const f32x4*)&stg[fp * 132 + q];
        *(f32x4*)(G0p + (size_t)fp * 131072 + m0b2 + q) = v;
    }
}

// one gaussian level: H pass (x) into H_t, V pass (y) accumulates into acc.
__device__ void blur_level(const float* in_t, float* H_t,
                           const float* kh_s, const float* kv_s,
                           int tid, float* acc, int S, int off) {
    int half = S / 2;
    int nrows = 31 + S;
    for (int g = tid; g < nrows * 8; g += 512) {
        int yy = (16 - half) + (g >> 3);
        int xg = g & 7;
        float a00 = 0.0f, a01 = 0.0f, a10 = 0.0f, a11 = 0.0f;
        float a20 = 0.0f, a21 = 0.0f, a30 = 0.0f, a31 = 0.0f;
        int cb = xg * 4 + 16 - half;
        for (int t = 0; t < S + 3; t++) {
            float v0 = in_t[(yy * 66 + cb + t) * 2 + 0];
            float v1 = in_t[(yy * 66 + cb + t) * 2 + 1];
            if (t < S)              { float k = kh_s[off + t];     a00 += k * v0; a01 += k * v1; }
            if (t >= 1 && t - 1 < S){ float k = kh_s[off + t - 1]; a10 += k * v0; a11 += k * v1; }
            if (t >= 2 && t - 2 < S){ float k = kh_s[off + t - 2]; a20 += k * v0; a21 += k * v1; }
            if (t >= 3 && t - 3 < S){ float k = kh_s[off + t - 3]; a30 += k * v0; a31 += k * v1; }
        }
        int hb = (yy * 33 + xg * 4) * 2;
        H_t[hb + 0] = a00; H_t[hb + 1] = a01;
        H_t[hb + 2] = a10; H_t[hb + 3] = a11;
        H_t[hb + 4] = a20; H_t[hb + 5] = a21;
        H_t[hb + 6] = a30; H_t[hb + 7] = a31;
    }
    __syncthreads();
    int xl = tid & 31;
    int ygrp = tid >> 5;
    int ybase = ygrp * 2 + 16 - half;
    for (int t = 0; t <= S; t++) {
        float h0 = H_t[((ybase + t) * 33 + xl) * 2 + 0];
        float h1 = H_t[((ybase + t) * 33 + xl) * 2 + 1];
        if (t < S)  { float k = kv_s[off + t];     acc[0] += k * h0; acc[1] += k * h1; }
        if (t >= 1) { float k = kv_s[off + t - 1]; acc[2] += k * h0; acc[3] += k * h1; }
    }
    __syncthreads();
}

// fused 6-level blur: 32x32 spatial tile x one feature-pair plane (f32 pair),
// halo 16 each side. 1D grid + XCD remap: bid%8 = XCD selector picks a group
// of 8 planes, so each plane's 64 spatial blocks run on ONE XCD and halo
// re-reads hit that XCD's L2. FROZEN R16 body.
__global__ void kblur(const float* G0p, const float* coef, float* Gb) {
    __shared__ float in_t[63 * 66 * 2];
    __shared__ float H_t[63 * 33 * 2];
    __shared__ float kh_s[64];
    __shared__ float kv_s[64];
    __shared__ float b0s[1];
    int tid = threadIdx.x;
    int bid = blockIdx.x;
    int xcd = bid & 7;
    int q = bid >> 3;                 // 0..511
    int fp = (xcd << 3) | (q >> 6);   // 8 planes per XCD, spatial inner
    int s = q & 63;
    int x0 = (s & 7) * 32;
    int y0 = (s >> 3) * 32;
    const float* Pin = G0p + (size_t)fp * 131072;
    float* Pout = Gb + (size_t)fp * 131072;
    if (tid < 64) { kh_s[tid] = coef[tid]; kv_s[tid] = coef[64 + tid]; }
    if (tid == 64) b0s[0] = coef[128];
    for (int i = tid; i < 63 * 63; i += 512) {
        int yy = i / 63;
        int xx = i - yy * 63;
        int gy = y0 + yy - 16; if (gy < 0) gy = -gy; if (gy > 255) gy = 510 - gy;
        int gx = x0 + xx - 16; if (gx < 0) gx = -gx; if (gx > 255) gx = 510 - gx;
        const float* src = Pin + (size_t)(gy * 256 + gx) * 2;
        in_t[(yy * 66 + xx) * 2 + 0] = src[0];
        in_t[(yy * 66 + xx) * 2 + 1] = src[1];
    }
    __syncthreads();
    int xl = tid & 31;
    int ygrp = tid >> 5;
    float acc[4];
    float b0 = b0s[0];
    acc[0] = b0 * in_t[((ygrp * 2 + 16) * 66 + xl + 16) * 2 + 0];
    acc[1] = b0 * in_t[((ygrp * 2 + 16) * 66 + xl + 16) * 2 + 1];
    acc[2] = b0 * in_t[((ygrp * 2 + 17) * 66 + xl + 16) * 2 + 0];
    acc[3] = b0 * in_t[((ygrp * 2 + 17) * 66 + xl + 16) * 2 + 1];
    blur_level(in_t, H_t, kh_s, kv_s, tid, acc, 2, 0);
    blur_level(in_t, H_t, kh_s, kv_s, tid, acc, 4, 2);
    blur_level(in_t, H_t, kh_s, kv_s, tid, acc, 8, 6);
    blur_level(in_t, H_t, kh_s, kv_s, tid, acc, 16, 14);
    blur_level(in_t, H_t, kh_s, kv_s, tid, acc, 32, 30);
    for (int i = 0; i < 2; i++) {
        int gy = y0 + ygrp * 2 + i;
        int gx = x0 + xl;
        float* dst = Pout + (size_t)(gy * 256 + gx) * 2;
        dst[0] = acc[i * 2 + 0];
        dst[1] = acc[i * 2 + 1];
    }
}

// f32 pair-planes (64 x 65536 x 2 f32) -> packed bf16 (y,x,fp=64 u32).
// LDS 32x65 pad; coalesced 64B-per-thread reads, 16B vector writes.
__global__ void ktrans(const float* Gb, unsigned int* G2) {
    __shared__ unsigned int lds[32 * 65];
    int t = threadIdx.x;
    int x0 = blockIdx.x * 32;
    int y = blockIdx.y;
    int base = y * 256 + x0;
    int fp = t >> 2;            // 0..63
    int p0 = (t & 3) * 8;       // 0,8,16,24
    const float* src = Gb + ((size_t)fp * 65536 + base + p0) * 2;
    for (int k4 = 0; k4 < 4; k4++) {
        f32x4 v = *(const f32x4*)(src + k4 * 4);   // 2 px (pair each)
        unsigned int u0 = ((unsigned int)f2bfbits(v[1]) << 16)
                        | (unsigned int)f2bfbits(v[0]);
        unsigned int u1 = ((unsigned int)f2bfbits(v[3]) << 16)
                        | (unsigned int)f2bfbits(v[2]);
        lds[(p0 + k4 * 2 + 0) * 65 + fp] = u0;
        lds[(p0 + k4 * 2 + 1) * 65 + fp] = u1;
    }
    __syncthreads();
    int px = t >> 3;            // 0..31
    int f0 = (t & 7) * 8;       // 0..56
    u32x4 o0, o1;
    o0[0] = lds[px * 65 + f0 + 0]; o0[1] = lds[px * 65 + f0 + 1];
    o0[2] = lds[px * 65 + f0 + 2]; o0[3] = lds[px * 65 + f0 + 3];
    o1[0] = lds[px * 65 + f0 + 4]; o1[1] = lds[px * 65 + f0 + 5];
    o1[2] = lds[px * 65 + f0 + 6]; o1[3] = lds[px * 65 + f0 + 7];
    unsigned int* dst = G2 + (size_t)(base + px) * 64 + f0;
    *(u32x4*)(dst) = o0;
    *(u32x4*)(dst + 4) = o1;
}

// gather: 4 points per wave (16 lanes each); lane s owns feature pairs
// {s, s+16, s+32, s+48} via FOUR SCALAR u32 loads per corner-row chunk --
// per wave-instruction: 4 points x 1 fully-used 64B line = same line
// efficiency as 2pt, but 16 independent loads/lane (2x ILP) and half the
// waves. shfl_xor width-16 tree; sub-lane 0 writes out (+b2). R28-proven.
__global__ void kgather(const float* pt, const unsigned int* G2,
                        const float* b1, const float* W2, const float* b2,
                        float* out) {
    int tid = threadIdx.x;
    int s = tid & 15;                 // 16 lanes per point
    int grp = tid >> 4;               // 0..15: 16 points per 256-thr block
    int i = blockIdx.x * 16 + grp;
    float py = pt[2 * i];
    float px = pt[2 * i + 1];
    float ay = (py + 1.0f) * 0.5f * 255.0f;
    float ax = (px + 1.0f) * 0.5f * 255.0f;
    int iy = (int)ay;
    int ix = (int)ax;
    if (iy < 0) iy = 0;
    if (iy > 255) iy = 255;
    if (ix < 0) ix = 0;
    if (ix > 255) ix = 255;
    float fy = ay - (float)iy;
    float fx = ax - (float)ix;
    int iy1 = iy + 1; if (iy1 > 255) iy1 = 255;
    int ix1 = ix + 1; if (ix1 > 255) ix1 = 255;
    float w00 = (1.0f - fy) * (1.0f - fx);
    float w01 = (1.0f - fy) * fx;
    float w10 = fy * (1.0f - fx);
    float w11 = fy * fx;
    const unsigned int* c00 = G2 + (size_t)(iy  * 256 + ix ) * 64;
    const unsigned int* c01 = G2 + (size_t)(iy  * 256 + ix1) * 64;
    const unsigned int* c10 = G2 + (size_t)(iy1 * 256 + ix ) * 64;
    const unsigned int* c11 = G2 + (size_t)(iy1 * 256 + ix1) * 64;
    unsigned int u00[4], u01[4], u10[4], u11[4];
#pragma unroll
    for (int j = 0; j < 4; j++) {
        int idx = s + 16 * j;
        u00[j] = c00[idx];
        u01[j] = c01[idx];
        u10[j] = c10[idx];
        u11[j] = c11[idx];
    }
    float o0 = 0.0f, o1 = 0.0f, o2 = 0.0f, o3 = 0.0f;
#pragma unroll
    for (int j = 0; j < 4; j++) {
        int f = (s + 16 * j) * 2;
        float v0 = w00 * bflo(u00[j]) + w01 * bflo(u01[j])
                 + w10 * bflo(u10[j]) + w11 * bflo(u11[j]) + b1[f];
        float v1 = w00 * bfhi(u00[j]) + w01 * bfhi(u01[j])
                 + w10 * bfhi(u10[j]) + w11 * bfhi(u11[j]) + b1[f + 1];
        if (v0 < 0.0f) v0 = 0.0f;
        if (v1 < 0.0f) v1 = 0.0f;
        o0 += v0 * W2[f * 4 + 0] + v1 * W2[f * 4 + 4];
        o1 += v0 * W2[f * 4 + 1] + v1 * W2[f * 4 + 5];
        o2 += v0 * W2[f * 4 + 2] + v1 * W2[f * 4 + 6];
        o3 += v0 * W2[f * 4 + 3] + v1 * W2[f * 4 + 7];
    }
    for (int m = 8; m >= 1; m >>= 1) {
        o0 += __shfl_xor(o0, m, 16);
        o1 += __shfl_xor(o1, m, 16);
        o2 += __shfl_xor(o2, m, 16);
        o3 += __shfl_xor(o3, m, 16);
    }
    if (s == 0) {
        out[4 * i + 0] = o0 + b2[0];
        out[4 * i + 1] = o1 + b2[1];
        out[4 * i + 2] = o2 + b2[2];
        out[4 * i + 3] = o3 + b2[3];
    }
}

extern "C" void kernel_launch(void* const* d_in, const int* in_sizes, int n_in,
                              void* d_out, int out_size, void* d_ws, size_t ws_size,
                              hipStream_t stream) {
    const float* pt   = (const float*)d_in[0];
    const float* base = (const float*)d_in[1];
    const float* blev = (const float*)d_in[2];
    const float* W1   = (const float*)d_in[3];
    const float* b1   = (const float*)d_in[4];
    const float* W2   = (const float*)d_in[5];
    const float* b2   = (const float*)d_in[6];
    if (n_in == 7) {
        for (int i = 0; i < 7; i++) {
            int sz = in_sizes[i];
            if (sz == 524288)       pt   = (const float*)d_in[i];
            else if (sz == 8388608) base = (const float*)d_in[i];
            else if (sz == 6)       blev = (const float*)d_in[i];
            else if (sz == 16384)   W1   = (const float*)d_in[i];
            else if (sz == 128)     b1   = (const float*)d_in[i];
            else if (sz == 512)     W2   = (const float*)d_in[i];
            else if (sz == 4)       b2   = (const float*)d_in[i];
        }
    }
    float* out = (float*)d_out;
    char* ws = (char*)d_ws;

    // ws: coef 1 KB | W1T 64 KB | G0p 32 MiB f32 | Gb 32 MiB f32 | G2 16 MiB
    size_t off0 = 1024;
    size_t off1 = off0 + 65536;
    size_t off2 = off1 + 33554432;
    size_t off3 = off2 + 33554432;
    size_t need = off3 + 16777216;
    if (ws_size < need) return;

    float* coef = (float*)ws;
    unsigned short* W1T = (unsigned short*)(ws + off0);
    float* G0p = (float*)(ws + off1);                // f32 pair-planes
    float* Gb  = (float*)(ws + off2);                // f32 pair-planes blurred
    unsigned int* G2 = (unsigned int*)(ws + off3);   // packed bf16 (y,x,fp)

    kconvW<<<64, 256, 0, stream>>>(W1, W1T, blev, coef);
    kgemm<<<1024, 512, 0, stream>>>(base, W1T, G0p);
    kblur<<<4096, 512, 0, stream>>>(G0p, coef, Gb);
    ktrans<<<dim3(8, 256), 256, 0, stream>>>(Gb, G2);
    kgather<<<16384, 256, 0, stream>>>(pt, G2, b1, W2, b2, out);
}

// Round 18
// 287.670 us; speedup vs baseline: 1.0152x; 1.0152x over previous
//
#include <hip/hip_runtime.h>

// MipMap: out = relu(interp(G)+b1)@W2 + b2, G = sum_l b_l * blur_l(base@W1).
// Blur acts on spatial axes, W1 on the feature axis -> commute; interp linear.
// FINAL CONFIG = R30 (PASSED 287.9, best). R31 (8-wave kgemm) 292 REGRESSED
// -> kgemm is A-load-latency-pinned (both VALU-bound and occupancy-bound
// hypotheses refuted); restructuring = codegen-regime risk (kblur saga).
// Ledger 452 -> 287.9 (1.57x): plane layout (R14), plane->XCD affinity
// (R16), kcoef fold (R27), 2pt -> scalar-4pt gather (R24/R28), cvt_pk
// (R30). kblur FROZEN at R16 bit-exact body (141us / FETCH 134 / WRITE 365,
// 6x reproduced): counted-traffic regime is source-invariant (7 refuted
// interventions); LDS/occupancy variants all regress. kgather at its
// line-efficiency/ILP sweet spot (vector-4pt and 8pt both bounded out).
// Style: no cstdint, no unions, no templates (R9's build-fix delta).

typedef short short8 __attribute__((ext_vector_type(8)));
typedef float f32x4 __attribute__((ext_vector_type(4)));
typedef unsigned int u32x4 __attribute__((ext_vector_type(4)));

__device__ __forceinline__ unsigned short f2bfbits(float f) {
    unsigned int x = __float_as_uint(f);
    x += 0x7fffu + ((x >> 16) & 1u);   // round-to-nearest-even
    return (unsigned short)(x >> 16);
}

__device__ __forceinline__ unsigned int cvtpk_bf16(float lo, float hi) {
    unsigned int r;
    asm("v_cvt_pk_bf16_f32 %0, %1, %2" : "=v"(r) : "v"(lo), "v"(hi));
    return r;
}

__device__ __forceinline__ float bflo(unsigned int u) {
    return __uint_as_float(u << 16);
}

__device__ __forceinline__ float bfhi(unsigned int u) {
    return __uint_as_float(u & 0xffff0000u);
}

// W1 (k,n) f32 -> W1T (n,k) bf16; thread (0,0) additionally builds the coef
// table (independent output, no sync needed): coef[0..63] horiz taps,
// coef[64..127] vert taps * b_level, coef[128] b0.
__global__ void kconvW(const float* W1, unsigned short* W1T,
                       const float* blev, float* coef) {
    int i = blockIdx.x * 256 + threadIdx.x;   // 16384
    int k = i >> 7;
    int n = i & 127;
    W1T[n * 128 + k] = f2bfbits(W1[i]);
    if (blockIdx.x == 0 && threadIdx.x == 0) {
        int offs[6];
        offs[0] = 0; offs[1] = 0; offs[2] = 2; offs[3] = 6; offs[4] = 14; offs[5] = 30;
        for (int l = 1; l <= 5; l++) {
            int s = 1 << l;
            int off = offs[l];
            float sum = 0.0f;
            for (int m = 0; m < s; m++) {
                float x = ((float)m - (float)(s - 1) * 0.5f) / ((float)s * 0.5f);
                float w = expf(-0.5f * x * x);
                coef[off + m] = w;
                sum += w;
            }
            float bl = blev[l];
            for (int m = 0; m < s; m++) {
                float w = coef[off + m] / sum;
                coef[off + m] = w;
                coef[64 + off + m] = w * bl;
            }
        }
        coef[128] = blev[0];
    }
}

// MFMA GEMM: G0p(64 planes of 65536 x 2 f32) = base @ W1, plane layout.
// base f32 loaded directly; A-fragment converted via v_cvt_pk_bf16_f32.
// Wave = 16 rows x 128 cols (8 tiles 16x16, K-loop 4x32). D: m_off=quad*4+r,
// n=c*16+(lane&15) (guide-verified m89/m91). Epilogue stages the 64x128
// tile in LDS (stride 132), writes f32 pair-planes (R16-proven shape).
__global__ void kgemm(const float* base, const unsigned short* W1T,
                      float* G0p) {
    __shared__ float stg[64 * 132];
    int tid = threadIdx.x;
    int wv = tid >> 6;
    int lane = tid & 63;
    int colI = lane & 15;
    int quad = lane >> 4;
    int m0 = blockIdx.x * 64 + wv * 16;
    f32x4 zero = {0.0f, 0.0f, 0.0f, 0.0f};
    f32x4 acc0 = zero; f32x4 acc1 = zero; f32x4 acc2 = zero; f32x4 acc3 = zero;
    f32x4 acc4 = zero; f32x4 acc5 = zero; f32x4 acc6 = zero; f32x4 acc7 = zero;
    for (int kc = 0; kc < 4; kc++) {
        int k0 = kc * 32 + quad * 8;
        const float* ap = base + (size_t)(m0 + colI) * 128 + k0;
        f32x4 af0 = *(const f32x4*)(ap);
        f32x4 af1 = *(const f32x4*)(ap + 4);
        u32x4 au;
        au[0] = cvtpk_bf16(af0[0], af0[1]);
        au[1] = cvtpk_bf16(af0[2], af0[3]);
        au[2] = cvtpk_bf16(af1[0], af1[1]);
        au[3] = cvtpk_bf16(af1[2], af1[3]);
        short8 a = *(short8*)&au;
        const unsigned short* wb = W1T + (size_t)colI * 128 + k0;
        short8 b0 = *(const short8*)(wb + 0 * 16 * 128);
        short8 b1 = *(const short8*)(wb + 1 * 16 * 128);
        short8 b2 = *(const short8*)(wb + 2 * 16 * 128);
        short8 b3 = *(const short8*)(wb + 3 * 16 * 128);
        short8 b4 = *(const short8*)(wb + 4 * 16 * 128);
        short8 b5 = *(const short8*)(wb + 5 * 16 * 128);
        short8 b6 = *(const short8*)(wb + 6 * 16 * 128);
        short8 b7 = *(const short8*)(wb + 7 * 16 * 128);
        acc0 = __builtin_amdgcn_mfma_f32_16x16x32_bf16(a, b0, acc0, 0, 0, 0);
        acc1 = __builtin_amdgcn_mfma_f32_16x16x32_bf16(a, b1, acc1, 0, 0, 0);
        acc2 = __builtin_amdgcn_mfma_f32_16x16x32_bf16(a, b2, acc2, 0, 0, 0);
        acc3 = __builtin_amdgcn_mfma_f32_16x16x32_bf16(a, b3, acc3, 0, 0, 0);
        acc4 = __builtin_amdgcn_mfma_f32_16x16x32_bf16(a, b4, acc4, 0, 0, 0);
        acc5 = __builtin_amdgcn_mfma_f32_16x16x32_bf16(a, b5, acc5, 0, 0, 0);
        acc6 = __builtin_amdgcn_mfma_f32_16x16x32_bf16(a, b6, acc6, 0, 0, 0);
        acc7 = __builtin_amdgcn_mfma_f32_16x16x32_bf16(a, b7, acc7, 0, 0, 0);
    }
    // stage to LDS: stg[(n>>1)*132 + m_local*2 + (n&1)], m_local in [0,64)
    int mlb = (wv * 16 + quad * 4) * 2;
#define STG(c, A) { int n = c * 16 + colI; \
    float* p = stg + (n >> 1) * 132 + mlb + (n & 1); \
    p[0] = A[0]; p[2] = A[1]; p[4] = A[2]; p[6] = A[3]; }
    STG(0, acc0) STG(1, acc1) STG(2, acc2) STG(3, acc3)
    STG(4, acc4) STG(5, acc5) STG(6, acc6) STG(7, acc7)
#undef STG
    __syncthreads();
    size_t m0b2 = (size_t)blockIdx.x * 128;   // m0_block * 2
    for (int j = tid; j < 2048; j += 256) {
        int fp = j >> 5;
        int q = (j & 31) * 4;
        f32x4 v = *(const f32x4*)&stg[fp * 132 + q];
        *(f32x4*)(G0p + (size_t)fp * 131072 + m0b2 + q) = v;
    }
}

// one gaussian level: H pass (x) into H_t, V pass (y) accumulates into acc.
__device__ void blur_level(const float* in_t, float* H_t,
                           const float* kh_s, const float* kv_s,
                           int tid, float* acc, int S, int off) {
    int half = S / 2;
    int nrows = 31 + S;
    for (int g = tid; g < nrows * 8; g += 512) {
        int yy = (16 - half) + (g >> 3);
        int xg = g & 7;
        float a00 = 0.0f, a01 = 0.0f, a10 = 0.0f, a11 = 0.0f;
        float a20 = 0.0f, a21 = 0.0f, a30 = 0.0f, a31 = 0.0f;
        int cb = xg * 4 + 16 - half;
        for (int t = 0; t < S + 3; t++) {
            float v0 = in_t[(yy * 66 + cb + t) * 2 + 0];
            float v1 = in_t[(yy * 66 + cb + t) * 2 + 1];
            if (t < S)              { float k = kh_s[off + t];     a00 += k * v0; a01 += k * v1; }
            if (t >= 1 && t - 1 < S){ float k = kh_s[off + t - 1]; a10 += k * v0; a11 += k * v1; }
            if (t >= 2 && t - 2 < S){ float k = kh_s[off + t - 2]; a20 += k * v0; a21 += k * v1; }
            if (t >= 3 && t - 3 < S){ float k = kh_s[off + t - 3]; a30 += k * v0; a31 += k * v1; }
        }
        int hb = (yy * 33 + xg * 4) * 2;
        H_t[hb + 0] = a00; H_t[hb + 1] = a01;
        H_t[hb + 2] = a10; H_t[hb + 3] = a11;
        H_t[hb + 4] = a20; H_t[hb + 5] = a21;
        H_t[hb + 6] = a30; H_t[hb + 7] = a31;
    }
    __syncthreads();
    int xl = tid & 31;
    int ygrp = tid >> 5;
    int ybase = ygrp * 2 + 16 - half;
    for (int t = 0; t <= S; t++) {
        float h0 = H_t[((ybase + t) * 33 + xl) * 2 + 0];
        float h1 = H_t[((ybase + t) * 33 + xl) * 2 + 1];
        if (t < S)  { float k = kv_s[off + t];     acc[0] += k * h0; acc[1] += k * h1; }
        if (t >= 1) { float k = kv_s[off + t - 1]; acc[2] += k * h0; acc[3] += k * h1; }
    }
    __syncthreads();
}

// fused 6-level blur: 32x32 spatial tile x one feature-pair plane (f32 pair),
// halo 16 each side. 1D grid + XCD remap: bid%8 = XCD selector picks a group
// of 8 planes, so each plane's 64 spatial blocks run on ONE XCD and halo
// re-reads hit that XCD's L2. FROZEN R16 body.
__global__ void kblur(const float* G0p, const float* coef, float* Gb) {
    __shared__ float in_t[63 * 66 * 2];
    __shared__ float H_t[63 * 33 * 2];
    __shared__ float kh_s[64];
    __shared__ float kv_s[64];
    __shared__ float b0s[1];
    int tid = threadIdx.x;
    int bid = blockIdx.x;
    int xcd = bid & 7;
    int q = bid >> 3;                 // 0..511
    int fp = (xcd << 3) | (q >> 6);   // 8 planes per XCD, spatial inner
    int s = q & 63;
    int x0 = (s & 7) * 32;
    int y0 = (s >> 3) * 32;
    const float* Pin = G0p + (size_t)fp * 131072;
    float* Pout = Gb + (size_t)fp * 131072;
    if (tid < 64) { kh_s[tid] = coef[tid]; kv_s[tid] = coef[64 + tid]; }
    if (tid == 64) b0s[0] = coef[128];
    for (int i = tid; i < 63 * 63; i += 512) {
        int yy = i / 63;
        int xx = i - yy * 63;
        int gy = y0 + yy - 16; if (gy < 0) gy = -gy; if (gy > 255) gy = 510 - gy;
        int gx = x0 + xx - 16; if (gx < 0) gx = -gx; if (gx > 255) gx = 510 - gx;
        const float* src = Pin + (size_t)(gy * 256 + gx) * 2;
        in_t[(yy * 66 + xx) * 2 + 0] = src[0];
        in_t[(yy * 66 + xx) * 2 + 1] = src[1];
    }
    __syncthreads();
    int xl = tid & 31;
    int ygrp = tid >> 5;
    float acc[4];
    float b0 = b0s[0];
    acc[0] = b0 * in_t[((ygrp * 2 + 16) * 66 + xl + 16) * 2 + 0];
    acc[1] = b0 * in_t[((ygrp * 2 + 16) * 66 + xl + 16) * 2 + 1];
    acc[2] = b0 * in_t[((ygrp * 2 + 17) * 66 + xl + 16) * 2 + 0];
    acc[3] = b0 * in_t[((ygrp * 2 + 17) * 66 + xl + 16) * 2 + 1];
    blur_level(in_t, H_t, kh_s, kv_s, tid, acc, 2, 0);
    blur_level(in_t, H_t, kh_s, kv_s, tid, acc, 4, 2);
    blur_level(in_t, H_t, kh_s, kv_s, tid, acc, 8, 6);
    blur_level(in_t, H_t, kh_s, kv_s, tid, acc, 16, 14);
    blur_level(in_t, H_t, kh_s, kv_s, tid, acc, 32, 30);
    for (int i = 0; i < 2; i++) {
        int gy = y0 + ygrp * 2 + i;
        int gx = x0 + xl;
        float* dst = Pout + (size_t)(gy * 256 + gx) * 2;
        dst[0] = acc[i * 2 + 0];
        dst[1] = acc[i * 2 + 1];
    }
}

// f32 pair-planes (64 x 65536 x 2 f32) -> packed bf16 (y,x,fp=64 u32).
// LDS 32x65 pad; coalesced 64B-per-thread reads, 16B vector writes.
__global__ void ktrans(const float* Gb, unsigned int* G2) {
    __shared__ unsigned int lds[32 * 65];
    int t = threadIdx.x;
    int x0 = blockIdx.x * 32;
    int y = blockIdx.y;
    int base = y * 256 + x0;
    int fp = t >> 2;            // 0..63
    int p0 = (t & 3) * 8;       // 0,8,16,24
    const float* src = Gb + ((size_t)fp * 65536 + base + p0) * 2;
    for (int k4 = 0; k4 < 4; k4++) {
        f32x4 v = *(const f32x4*)(src + k4 * 4);   // 2 px (pair each)
        unsigned int u0 = ((unsigned int)f2bfbits(v[1]) << 16)
                        | (unsigned int)f2bfbits(v[0]);
        unsigned int u1 = ((unsigned int)f2bfbits(v[3]) << 16)
                        | (unsigned int)f2bfbits(v[2]);
        lds[(p0 + k4 * 2 + 0) * 65 + fp] = u0;
        lds[(p0 + k4 * 2 + 1) * 65 + fp] = u1;
    }
    __syncthreads();
    int px = t >> 3;            // 0..31
    int f0 = (t & 7) * 8;       // 0..56
    u32x4 o0, o1;
    o0[0] = lds[px * 65 + f0 + 0]; o0[1] = lds[px * 65 + f0 + 1];
    o0[2] = lds[px * 65 + f0 + 2]; o0[3] = lds[px * 65 + f0 + 3];
    o1[0] = lds[px * 65 + f0 + 4]; o1[1] = lds[px * 65 + f0 + 5];
    o1[2] = lds[px * 65 + f0 + 6]; o1[3] = lds[px * 65 + f0 + 7];
    unsigned int* dst = G2 + (size_t)(base + px) * 64 + f0;
    *(u32x4*)(dst) = o0;
    *(u32x4*)(dst + 4) = o1;
}

// gather: 4 points per wave (16 lanes each); lane s owns feature pairs
// {s, s+16, s+32, s+48} via FOUR SCALAR u32 loads per corner-row chunk --
// per wave-instruction: 4 points x 1 fully-used 64B line = same line
// efficiency as 2pt, but 16 independent loads/lane (2x ILP) and half the
// waves. shfl_xor width-16 tree; sub-lane 0 writes out (+b2). R28-proven.
__global__ void kgather(const float* pt, const unsigned int* G2,
                        const float* b1, const float* W2, const float* b2,
                        float* out) {
    int tid = threadIdx.x;
    int s = tid & 15;                 // 16 lanes per point
    int grp = tid >> 4;               // 0..15: 16 points per 256-thr block
    int i = blockIdx.x * 16 + grp;
    float py = pt[2 * i];
    float px = pt[2 * i + 1];
    float ay = (py + 1.0f) * 0.5f * 255.0f;
    float ax = (px + 1.0f) * 0.5f * 255.0f;
    int iy = (int)ay;
    int ix = (int)ax;
    if (iy < 0) iy = 0;
    if (iy > 255) iy = 255;
    if (ix < 0) ix = 0;
    if (ix > 255) ix = 255;
    float fy = ay - (float)iy;
    float fx = ax - (float)ix;
    int iy1 = iy + 1; if (iy1 > 255) iy1 = 255;
    int ix1 = ix + 1; if (ix1 > 255) ix1 = 255;
    float w00 = (1.0f - fy) * (1.0f - fx);
    float w01 = (1.0f - fy) * fx;
    float w10 = fy * (1.0f - fx);
    float w11 = fy * fx;
    const unsigned int* c00 = G2 + (size_t)(iy  * 256 + ix ) * 64;
    const unsigned int* c01 = G2 + (size_t)(iy  * 256 + ix1) * 64;
    const unsigned int* c10 = G2 + (size_t)(iy1 * 256 + ix ) * 64;
    const unsigned int* c11 = G2 + (size_t)(iy1 * 256 + ix1) * 64;
    unsigned int u00[4], u01[4], u10[4], u11[4];
#pragma unroll
    for (int j = 0; j < 4; j++) {
        int idx = s + 16 * j;
        u00[j] = c00[idx];
        u01[j] = c01[idx];
        u10[j] = c10[idx];
        u11[j] = c11[idx];
    }
    float o0 = 0.0f, o1 = 0.0f, o2 = 0.0f, o3 = 0.0f;
#pragma unroll
    for (int j = 0; j < 4; j++) {
        int f = (s + 16 * j) * 2;
        float v0 = w00 * bflo(u00[j]) + w01 * bflo(u01[j])
                 + w10 * bflo(u10[j]) + w11 * bflo(u11[j]) + b1[f];
        float v1 = w00 * bfhi(u00[j]) + w01 * bfhi(u01[j])
                 + w10 * bfhi(u10[j]) + w11 * bfhi(u11[j]) + b1[f + 1];
        if (v0 < 0.0f) v0 = 0.0f;
        if (v1 < 0.0f) v1 = 0.0f;
        o0 += v0 * W2[f * 4 + 0] + v1 * W2[f * 4 + 4];
        o1 += v0 * W2[f * 4 + 1] + v1 * W2[f * 4 + 5];
        o2 += v0 * W2[f * 4 + 2] + v1 * W2[f * 4 + 6];
        o3 += v0 * W2[f * 4 + 3] + v1 * W2[f * 4 + 7];
    }
    for (int m = 8; m >= 1; m >>= 1) {
        o0 += __shfl_xor(o0, m, 16);
        o1 += __shfl_xor(o1, m, 16);
        o2 += __shfl_xor(o2, m, 16);
        o3 += __shfl_xor(o3, m, 16);
    }
    if (s == 0) {
        out[4 * i + 0] = o0 + b2[0];
        out[4 * i + 1] = o1 + b2[1];
        out[4 * i + 2] = o2 + b2[2];
        out[4 * i + 3] = o3 + b2[3];
    }
}

extern "C" void kernel_launch(void* const* d_in, const int* in_sizes, int n_in,
                              void* d_out, int out_size, void* d_ws, size_t ws_size,
                              hipStream_t stream) {
    const float* pt   = (const float*)d_in[0];
    const float* base = (const float*)d_in[1];
    const float* blev = (const float*)d_in[2];
    const float* W1   = (const float*)d_in[3];
    const float* b1   = (const float*)d_in[4];
    const float* W2   = (const float*)d_in[5];
    const float* b2   = (const float*)d_in[6];
    if (n_in == 7) {
        for (int i = 0; i < 7; i++) {
            int sz = in_sizes[i];
            if (sz == 524288)       pt   = (const float*)d_in[i];
            else if (sz == 8388608) base = (const float*)d_in[i];
            else if (sz == 6)       blev = (const float*)d_in[i];
            else if (sz == 16384)   W1   = (const float*)d_in[i];
            else if (sz == 128)     b1   = (const float*)d_in[i];
            else if (sz == 512)     W2   = (const float*)d_in[i];
            else if (sz == 4)       b2   = (const float*)d_in[i];
        }
    }
    float* out = (float*)d_out;
    char* ws = (char*)d_ws;

    // ws: coef 1 KB | W1T 64 KB | G0p 32 MiB f32 | Gb 32 MiB f32 | G2 16 MiB
    size_t off0 = 1024;
    size_t off1 = off0 + 65536;
    size_t off2 = off1 + 33554432;
    size_t off3 = off2 + 33554432;
    size_t need = off3 + 16777216;
    if (ws_size < need) return;

    float* coef = (float*)ws;
    unsigned short* W1T = (unsigned short*)(ws + off0);
    float* G0p = (float*)(ws + off1);                // f32 pair-planes
    float* Gb  = (float*)(ws + off2);                // f32 pair-planes blurred
    unsigned int* G2 = (unsigned int*)(ws + off3);   // packed bf16 (y,x,fp)

    kconvW<<<64, 256, 0, stream>>>(W1, W1T, blev, coef);
    kgemm<<<1024, 256, 0, stream>>>(base, W1T, G0p);
    kblur<<<4096, 512, 0, stream>>>(G0p, coef, Gb);
    ktrans<<<dim3(8, 256), 256, 0, stream>>>(Gb, G2);
    kgather<<<16384, 256, 0, stream>>>(pt, G2, b1, W2, b2, out);
}